// Round 13
// baseline (269.945 us; speedup 1.0000x reference)
//
#include <hip/hip_runtime.h>
#include <stdint.h>

#define WB 8
#define WC 32
#define WU 32
#define WK 5
#define WN 256
#define NN 65536     // 256*256
#define KC 160       // WK*WC
#define KQ 1280      // WK*WN

typedef __attribute__((ext_vector_type(8))) short bf8;     // 8 x bf16
typedef __attribute__((ext_vector_type(8))) unsigned short us8;
typedef __attribute__((ext_vector_type(4))) float f4;

__device__ __forceinline__ unsigned short f2b(float f) {
    union { float f; uint32_t u; } v; v.f = f;
    uint32_t u = v.u;
    return (unsigned short)((u + 0x7FFFu + ((u >> 16) & 1u)) >> 16);  // RNE
}

// async global->LDS, 16B per lane; lds base must be wave-uniform (m97 pattern)
__device__ __forceinline__ void gload16(const unsigned short* g, unsigned short* l) {
    __builtin_amdgcn_global_load_lds(
        (const __attribute__((address_space(1))) unsigned int*)g,
        (__attribute__((address_space(3))) unsigned int*)l, 16, 0, 0);
}

// ---------------------------------------------------------------------------
// P0: repacks (bf16): c1T[k][m][p], c2T[n][l*256+q], WtP fragment-packed
// ---------------------------------------------------------------------------
__global__ void prep_small(const float* __restrict__ cheb1,
                           const float* __restrict__ cheb2,
                           const float* __restrict__ coefs,
                           unsigned short* __restrict__ c1T,
                           unsigned short* __restrict__ c2T,
                           unsigned short* __restrict__ WtP) {
    int idx = blockIdx.x * 256 + threadIdx.x;
    if (idx < WK * NN) {            // c1T[k][m][p] = cheb1[k][p][m]
        int k = idx / NN, r = idx % NN, m = r / WN, p = r % WN;
        c1T[idx] = f2b(cheb1[(k * WN + p) * WN + m]);
    }
    if (idx < WN * KQ) {            // c2T[n][lq] = cheb2[lq][n]
        int n = idx / KQ, r = idx % KQ;
        c2T[idx] = f2b(cheb2[r * WN + n]);
    }
    if (idx < KC * KC) {            // fragment-packed Wt
        int e = idx & 7, lane = (idx >> 3) & 63, r = idx >> 9;   // r < 50
        int mf = r % 5, kk = (r / 5) % 5, mh = r / 25;
        int lu = mh * 80 + mf * 16 + (lane & 15);    // (l,u) row
        int ki = kk * 32 + (lane >> 4) * 8 + e;      // (k,i) col
        int l = lu >> 5, u = lu & 31, k = ki >> 5, i = ki & 31;
        WtP[idx] = f2b(coefs[((k * WK + l) * WC + i) * WU + u]);
    }
}

// ---------------------------------------------------------------------------
// P1: xT[b][i][q][p] (bf16) = x[b][i][p][q]
// ---------------------------------------------------------------------------
__global__ void prep_x(const float* __restrict__ x, unsigned short* __restrict__ xT) {
    __shared__ unsigned short tile[64][72];
    int bi = blockIdx.z;
    int p0 = blockIdx.y * 64, q0 = blockIdx.x * 64;
    const float* src = x + (size_t)bi * NN;
    unsigned short* dst = xT + (size_t)bi * NN;
    int t = threadIdx.x;
    int c4 = (t & 15) * 4, r0 = t >> 4;
    for (int it = 0; it < 4; ++it) {
        int r = r0 + it * 16;
        float4 v = *reinterpret_cast<const float4*>(&src[(size_t)(p0 + r) * WN + q0 + c4]);
        tile[r][c4 + 0] = f2b(v.x); tile[r][c4 + 1] = f2b(v.y);
        tile[r][c4 + 2] = f2b(v.z); tile[r][c4 + 3] = f2b(v.w);
    }
    __syncthreads();
    for (int it = 0; it < 4; ++it) {
        int q = r0 + it * 16;
        ushort4 o;
        o.x = tile[c4 + 0][q]; o.y = tile[c4 + 1][q];
        o.z = tile[c4 + 2][q]; o.w = tile[c4 + 3][q];
        *reinterpret_cast<ushort4*>(&dst[(size_t)(q0 + q) * WN + p0 + c4]) = o;
    }
}

// ---------------------------------------------------------------------------
// G1: per (b,i): a[(k*32+i)][m][q] = sum_p c1T[(k,m)][p] * xT[b,i][q][p]
//     r10 PASS version (unchanged): A dbuf, vmcnt(2), XCD-grouped swizzle.
// ---------------------------------------------------------------------------
__global__ __launch_bounds__(512, 4) void g1(const unsigned short* __restrict__ c1T,
                                             const unsigned short* __restrict__ xT,
                                             unsigned short* __restrict__ a, int b_base) {
    __shared__ unsigned short As[2][128 * 64];   // 32 KB
    __shared__ unsigned short Bs[256 * 64];      // 32 KB
    int p = blockIdx.x;
    int gpx = gridDim.x / 80;
    int xcd = p & 7, j = p >> 3;
    int grp = xcd * gpx + j / 10;           // bi group in [0, cur*32)
    int member = j % 10;                    // row-tile 0..9
    int bl = grp >> 5, i = grp & 31;
    int row0 = member * 128;                // (k,m) row base
    int b = b_base + bl;
    const unsigned short* Asrc = c1T;                              // pitch 256
    const unsigned short* Bsrc = xT + (size_t)(b * WC + i) * NN;   // [q][p], pitch 256
    unsigned short* Out = a + (size_t)bl * KC * NN;

    int t = threadIdx.x;
    int w = t >> 6, l = t & 63;
    int wm = (w >> 2) * 64, wn = (w & 3) * 64;
    int lr = l & 15, hi = l >> 4;
    int srow = l >> 3;                       // 0..7 within 8-row chunk
    int scol = ((l & 7) ^ srow) * 8;         // pre-swizzled source col (elems)

    f4 acc[4][4];
    for (int mf = 0; mf < 4; ++mf) for (int nf = 0; nf < 4; ++nf) acc[mf][nf] = (f4)(0.0f);

#define G1_STAGE_A(buf, step) do { \
    int p0_ = (step) * 64; \
    for (int it = 0; it < 2; ++it) { \
        int chunk = it * 8 + w; int row = chunk * 8 + srow; \
        gload16(&Asrc[(size_t)(row0 + row) * 256 + p0_ + scol], &As[buf][chunk * 512]); } \
} while (0)
#define G1_STAGE_B(step) do { \
    int p0_ = (step) * 64; \
    for (int it = 0; it < 4; ++it) { \
        int chunk = it * 8 + w; int row = chunk * 8 + srow; \
        gload16(&Bsrc[(size_t)row * 256 + p0_ + scol], &Bs[chunk * 512]); } \
} while (0)

    G1_STAGE_A(0, 0);                        // prologue: A(0) in flight
    for (int step = 0; step < 4; ++step) {
        int cur = step & 1;
        G1_STAGE_B(step);                    // B(t): 4 loads
        if (step < 3) {
            G1_STAGE_A(cur ^ 1, step + 1);   // A(t+1): 2 loads
            asm volatile("s_waitcnt vmcnt(2)" ::: "memory");
        } else {
            asm volatile("s_waitcnt vmcnt(0)" ::: "memory");
        }
        __builtin_amdgcn_s_barrier();        // tile t visible to all waves
        asm volatile("" ::: "memory");
        for (int kk = 0; kk < 2; ++kk) {
            bf8 af[4], bfr[4];
            for (int mf = 0; mf < 4; ++mf) {
                int r = wm + mf * 16 + lr;
                af[mf] = *(const bf8*)&As[cur][r * 64 + (((kk * 4 + hi) ^ (r & 7)) * 8)];
            }
            for (int nf = 0; nf < 4; ++nf) {
                int rb = wn + nf * 16 + lr;
                bfr[nf] = *(const bf8*)&Bs[rb * 64 + (((kk * 4 + hi) ^ (rb & 7)) * 8)];
            }
            for (int mf = 0; mf < 4; ++mf)
                for (int nf = 0; nf < 4; ++nf)
                    acc[mf][nf] = __builtin_amdgcn_mfma_f32_16x16x32_bf16(af[mf], bfr[nf], acc[mf][nf], 0, 0, 0);
        }
        asm volatile("" ::: "memory");
        __builtin_amdgcn_s_barrier();        // done reading Bs / As[cur]
    }
#undef G1_STAGE_A
#undef G1_STAGE_B
    for (int mf = 0; mf < 4; ++mf)
        for (int nf = 0; nf < 4; ++nf)
            for (int j2 = 0; j2 < 4; ++j2) {
                int grow = row0 + wm + mf * 16 + hi * 4 + j2;   // (k,m)
                int k = grow >> 8, m = grow & 255;
                int q = wn + nf * 16 + lr;
                Out[(size_t)(k * 32 + i) * NN + m * 256 + q] = f2b(acc[mf][nf][j2]);
            }
}

// ---------------------------------------------------------------------------
// G2P: c[(l,u)][(m,q)] = Wt @ a[ki][(m,q)]   (r12 PASS version, unchanged)
// ---------------------------------------------------------------------------
__global__ __launch_bounds__(512, 4) void g2p(const unsigned short* __restrict__ WtP,
                                              const unsigned short* __restrict__ a,
                                              unsigned short* __restrict__ c) {
    __shared__ unsigned short Bt[128 * 172];
    int bl = blockIdx.y;
    int n0 = blockIdx.x * 128;
    const unsigned short* asrc = a + (size_t)bl * KC * NN;
    unsigned short* Out = c + (size_t)bl * KC * NN;
    int t = threadIdx.x;

    for (int s = 0; s < 2; ++s) {
        int task = t + s * 512;
        if (task < 640) {
            int oct = task & 15, kq = task >> 4;
            const unsigned short* src = asrc + (size_t)(kq * 4) * NN + n0 + oct * 8;
            us8 v0 = *(const us8*)&src[0 * NN];
            us8 v1 = *(const us8*)&src[1 * NN];
            us8 v2 = *(const us8*)&src[2 * NN];
            us8 v3 = *(const us8*)&src[3 * NN];
            #pragma unroll
            for (int j = 0; j < 8; ++j) {
                ushort4 wv;
                wv.x = v0[j]; wv.y = v1[j]; wv.z = v2[j]; wv.w = v3[j];
                *reinterpret_cast<ushort4*>(&Bt[(oct * 8 + j) * 172 + kq * 4]) = wv;
            }
        }
    }
    __syncthreads();

    int w = t >> 6, l = t & 63;
    int mh = w >> 2, nq = w & 3;
    int lr = l & 15, hi = l >> 4;
    f4 acc[5][2];
    for (int mf = 0; mf < 5; ++mf) { acc[mf][0] = (f4)(0.0f); acc[mf][1] = (f4)(0.0f); }

    for (int kk = 0; kk < 5; ++kk) {
        int k0 = kk * 32 + hi * 8;
        bf8 bfr[2];
        #pragma unroll
        for (int nf = 0; nf < 2; ++nf) {
            int pix = (nq * 2 + nf) * 16 + lr;
            typedef __attribute__((ext_vector_type(4))) short s4v;
            s4v lo  = *(const s4v*)&Bt[pix * 172 + k0];
            s4v hi4 = *(const s4v*)&Bt[pix * 172 + k0 + 4];
            bfr[nf] = __builtin_shufflevector(lo, hi4, 0, 1, 2, 3, 4, 5, 6, 7);
        }
        #pragma unroll
        for (int mf = 0; mf < 5; ++mf) {
            bf8 afr = *(const bf8*)&WtP[(size_t)((((mh * 5 + kk) * 5 + mf) << 6) + l) * 8];
            acc[mf][0] = __builtin_amdgcn_mfma_f32_16x16x32_bf16(afr, bfr[0], acc[mf][0], 0, 0, 0);
            acc[mf][1] = __builtin_amdgcn_mfma_f32_16x16x32_bf16(afr, bfr[1], acc[mf][1], 0, 0, 0);
        }
    }
    for (int mf = 0; mf < 5; ++mf)
        for (int nf = 0; nf < 2; ++nf)
            for (int j = 0; j < 4; ++j) {
                int row = mh * 80 + mf * 16 + hi * 4 + j;       // (l,u)
                int col = n0 + (nq * 2 + nf) * 16 + lr;         // (m,q)
                Out[(size_t)row * NN + col] = f2b(acc[mf][nf][j]);
            }
}

// ---------------------------------------------------------------------------
// G3: out[b][u][m][n] = sum_{l,q} c[(l*32+u)][(m,q)] * c2T[n][(l,q)]
//     256x256 tile (BM = all m of one u, BN = all n), BK=64, 8 waves,
//     per-wave 128x64 (acc 8x4). LDS 128 KB = 2 slots x (A 32K + B 32K).
//     4-phase K-tile schedule: vmcnt(0)+barrier once per K-tile (loads
//     covered by a full K-tile of MFMA), then 4 phases each
//     {prefetch 1 half of t+1 into idle slot | ds_read quadrant | 16 MFMA
//      wrapped in setprio}. 20 K-tiles, 20 barriers total.
// ---------------------------------------------------------------------------
__global__ __launch_bounds__(512, 1) void g3(const unsigned short* __restrict__ c,
                                             const unsigned short* __restrict__ c2T,
                                             float* __restrict__ out, int b_base) {
    __shared__ unsigned short As[2][256 * 64];     // 64 KB
    __shared__ unsigned short Bs[2][256 * 64];     // 64 KB
    int bl = blockIdx.y;
    int b = b_base + bl;
    int u = blockIdx.x;                    // 32 u-tiles per batch
    const unsigned short* Csrc = c + (size_t)bl * KC * NN;

    int t_ = threadIdx.x;
    int w = t_ >> 6, l = t_ & 63;
    int wm = (w >> 2) * 128, wn = (w & 3) * 64;
    int lr = l & 15, hi = l >> 4;
    int srow = l >> 3;
    int scol = ((l & 7) ^ srow) * 8;

    f4 acc[8][4];
    for (int mf = 0; mf < 8; ++mf) for (int nf = 0; nf < 4; ++nf) acc[mf][nf] = (f4)(0.0f);

    // stage A half h (m-rows h*128..+128) of K-tile kt into slot s: 2 loads
#define ST_A(s, h, kt) do { \
    int lq_ = (kt) >> 2, q0_ = ((kt) & 3) * 64; \
    const unsigned short* base = Csrc + (size_t)(lq_ * 32 + u) * NN + q0_; \
    for (int it = 0; it < 2; ++it) { \
        int chunk = it * 8 + w; int row = (h) * 128 + chunk * 8 + srow; \
        gload16(&base[(size_t)row * 256 + scol], &As[s][(h) * 8192 + chunk * 512]); } \
} while (0)
    // stage B half h (n-rows h*128..+128) of K-tile kt into slot s: 2 loads
#define ST_B(s, h, kt) do { \
    const unsigned short* base = c2T + (size_t)((h) * 128) * KQ + (kt) * 64; \
    for (int it = 0; it < 2; ++it) { \
        int chunk = it * 8 + w; int rrow = chunk * 8 + srow; \
        gload16(&base[(size_t)rrow * KQ + scol], &Bs[s][(h) * 8192 + chunk * 512]); } \
} while (0)

    // prologue: tile 0 -> slot 0 (8 loads in flight)
    ST_A(0, 0, 0); ST_A(0, 1, 0); ST_B(0, 0, 0); ST_B(0, 1, 0);

    for (int t = 0; t < 20; ++t) {
        int s = t & 1;
        asm volatile("s_waitcnt vmcnt(0)" ::: "memory");  // tile t landed (mine)
        __builtin_amdgcn_s_barrier();                     // all waves: t landed,
        asm volatile("" ::: "memory");                    // t-1 reads done
        const unsigned short* A = As[s];
        const unsigned short* B = Bs[s];
        bf8 af[8], b0, b1;
        // ---- P0: kk=0, nf 0..1 ----
        if (t < 19) ST_A(s ^ 1, 0, t + 1);
        #pragma unroll
        for (int mf = 0; mf < 8; ++mf) {
            int r = wm + mf * 16 + lr;
            af[mf] = *(const bf8*)&A[r * 64 + ((hi ^ (r & 7)) * 8)];
        }
        { int rb = wn + lr;      b0 = *(const bf8*)&B[rb * 64 + ((hi ^ (rb & 7)) * 8)];
          rb = wn + 16 + lr;     b1 = *(const bf8*)&B[rb * 64 + ((hi ^ (rb & 7)) * 8)]; }
        __builtin_amdgcn_s_setprio(1);
        #pragma unroll
        for (int mf = 0; mf < 8; ++mf) {
            acc[mf][0] = __builtin_amdgcn_mfma_f32_16x16x32_bf16(af[mf], b0, acc[mf][0], 0, 0, 0);
            acc[mf][1] = __builtin_amdgcn_mfma_f32_16x16x32_bf16(af[mf], b1, acc[mf][1], 0, 0, 0);
        }
        __builtin_amdgcn_s_setprio(0);
        // ---- P1: kk=0, nf 2..3 ----
        if (t < 19) ST_A(s ^ 1, 1, t + 1);
        { int rb = wn + 32 + lr; b0 = *(const bf8*)&B[rb * 64 + ((hi ^ (rb & 7)) * 8)];
          rb = wn + 48 + lr;     b1 = *(const bf8*)&B[rb * 64 + ((hi ^ (rb & 7)) * 8)]; }
        __builtin_amdgcn_s_setprio(1);
        #pragma unroll
        for (int mf = 0; mf < 8; ++mf) {
            acc[mf][2] = __builtin_amdgcn_mfma_f32_16x16x32_bf16(af[mf], b0, acc[mf][2], 0, 0, 0);
            acc[mf][3] = __builtin_amdgcn_mfma_f32_16x16x32_bf16(af[mf], b1, acc[mf][3], 0, 0, 0);
        }
        __builtin_amdgcn_s_setprio(0);
        // ---- P2: kk=1, nf 0..1 ----
        if (t < 19) ST_B(s ^ 1, 0, t + 1);
        #pragma unroll
        for (int mf = 0; mf < 8; ++mf) {
            int r = wm + mf * 16 + lr;
            af[mf] = *(const bf8*)&A[r * 64 + (((4 + hi) ^ (r & 7)) * 8)];
        }
        { int rb = wn + lr;      b0 = *(const bf8*)&B[rb * 64 + (((4 + hi) ^ (rb & 7)) * 8)];
          rb = wn + 16 + lr;     b1 = *(const bf8*)&B[rb * 64 + (((4 + hi) ^ (rb & 7)) * 8)]; }
        __builtin_amdgcn_s_setprio(1);
        #pragma unroll
        for (int mf = 0; mf < 8; ++mf) {
            acc[mf][0] = __builtin_amdgcn_mfma_f32_16x16x32_bf16(af[mf], b0, acc[mf][0], 0, 0, 0);
            acc[mf][1] = __builtin_amdgcn_mfma_f32_16x16x32_bf16(af[mf], b1, acc[mf][1], 0, 0, 0);
        }
        __builtin_amdgcn_s_setprio(0);
        // ---- P3: kk=1, nf 2..3 ----
        if (t < 19) ST_B(s ^ 1, 1, t + 1);
        { int rb = wn + 32 + lr; b0 = *(const bf8*)&B[rb * 64 + (((4 + hi) ^ (rb & 7)) * 8)];
          rb = wn + 48 + lr;     b1 = *(const bf8*)&B[rb * 64 + (((4 + hi) ^ (rb & 7)) * 8)]; }
        __builtin_amdgcn_s_setprio(1);
        #pragma unroll
        for (int mf = 0; mf < 8; ++mf) {
            acc[mf][2] = __builtin_amdgcn_mfma_f32_16x16x32_bf16(af[mf], b0, acc[mf][2], 0, 0, 0);
            acc[mf][3] = __builtin_amdgcn_mfma_f32_16x16x32_bf16(af[mf], b1, acc[mf][3], 0, 0, 0);
        }
        __builtin_amdgcn_s_setprio(0);
        asm volatile("" ::: "memory");
    }
#undef ST_A
#undef ST_B
    for (int mf = 0; mf < 8; ++mf)
        for (int nf = 0; nf < 4; ++nf)
            for (int j = 0; j < 4; ++j) {
                int m = wm + mf * 16 + hi * 4 + j;
                int n = wn + nf * 16 + lr;
                out[((size_t)(b * WU + u) * WN + m) * WN + n] = acc[mf][nf][j];
            }
}

// ---------------------------------------------------------------------------
extern "C" void kernel_launch(void* const* d_in, const int* in_sizes, int n_in,
                              void* d_out, int out_size, void* d_ws, size_t ws_size,
                              hipStream_t stream) {
    const float* x     = (const float*)d_in[0];
    const float* cheb1 = (const float*)d_in[1];
    const float* cheb2 = (const float*)d_in[2];
    const float* coefs = (const float*)d_in[3];
    float* out = (float*)d_out;
    unsigned short* ws = (unsigned short*)d_ws;

    size_t off = 0;
    unsigned short* xT  = ws + off; off += (size_t)WB * WC * NN;
    unsigned short* c1T = ws + off; off += (size_t)WK * NN;
    unsigned short* c2T = ws + off; off += (size_t)WN * KQ;
    unsigned short* WtP = ws + off; off += (size_t)KC * KC;
    size_t fixed_elems = off;
    size_t a1 = (size_t)KC * NN;                 // one batch of a or c (elems)

    prep_small<<<1280, 256, 0, stream>>>(cheb1, cheb2, coefs, c1T, c2T, WtP);
    prep_x<<<dim3(4, 4, WB * WC), 256, 0, stream>>>(x, xT);

    size_t avail = ws_size / 2;
    size_t rem = avail > fixed_elems ? avail - fixed_elems : 0;

    if (rem >= 9 * a1) {
        // full-c path: chunk a by nb batches, single g3 over all 8
        int nb = (int)((rem - 8 * a1) / a1);
        if (nb < 1) nb = 1;
        if (nb > WB) nb = WB;
        unsigned short* a_ = ws + fixed_elems;
        unsigned short* c_ = a_ + (size_t)nb * a1;
        for (int b0 = 0; b0 < WB; b0 += nb) {
            int cur = (WB - b0 < nb) ? (WB - b0) : nb;
            g1<<<dim3(cur * 320), 512, 0, stream>>>(c1T, xT, a_, b0);
            g2p<<<dim3(512, cur), 512, 0, stream>>>(WtP, a_, c_ + (size_t)b0 * a1);
        }
        g3<<<dim3(32, WB), 512, 0, stream>>>(c_, c2T, out, 0);
    } else {
        // chunked fallback
        size_t per_b = 2 * a1;
        int nb = (int)(rem / per_b);
        if (nb < 1) nb = 1;
        if (nb > WB) nb = WB;
        unsigned short* a_ = ws + fixed_elems;
        unsigned short* c_ = a_ + (size_t)nb * a1;
        for (int b0 = 0; b0 < WB; b0 += nb) {
            int cur = (WB - b0 < nb) ? (WB - b0) : nb;
            g1<<<dim3(cur * 320), 512, 0, stream>>>(c1T, xT, a_, b0);
            g2p<<<dim3(512, cur), 512, 0, stream>>>(WtP, a_, c_);
            g3<<<dim3(32, cur), 512, 0, stream>>>(c_, c2T, out, b0);
        }
    }
}

// Round 14
// 268.222 us; speedup vs baseline: 1.0064x; 1.0064x over previous
//
#include <hip/hip_runtime.h>
#include <stdint.h>

#define WB 8
#define WC 32
#define WU 32
#define WK 5
#define WN 256
#define NN 65536     // 256*256
#define KC 160       // WK*WC
#define KQ 1280      // WK*WN

typedef __attribute__((ext_vector_type(8))) short bf8;     // 8 x bf16
typedef __attribute__((ext_vector_type(8))) unsigned short us8;
typedef __attribute__((ext_vector_type(4))) float f4;

__device__ __forceinline__ unsigned short f2b(float f) {
    union { float f; uint32_t u; } v; v.f = f;
    uint32_t u = v.u;
    return (unsigned short)((u + 0x7FFFu + ((u >> 16) & 1u)) >> 16);  // RNE
}

// async global->LDS, 16B per lane; lds base must be wave-uniform (m97 pattern)
__device__ __forceinline__ void gload16(const unsigned short* g, unsigned short* l) {
    __builtin_amdgcn_global_load_lds(
        (const __attribute__((address_space(1))) unsigned int*)g,
        (__attribute__((address_space(3))) unsigned int*)l, 16, 0, 0);
}

// ---------------------------------------------------------------------------
// P0+P1 merged: xT transpose + c1T/c2T/WtP repacks in ONE dispatch.
//   blocks 0..4095: prep_x tile;  blocks 0..1279 additionally do repacks.
// ---------------------------------------------------------------------------
__global__ void prep_all(const float* __restrict__ x,
                         const float* __restrict__ cheb1,
                         const float* __restrict__ cheb2,
                         const float* __restrict__ coefs,
                         unsigned short* __restrict__ xT,
                         unsigned short* __restrict__ c1T,
                         unsigned short* __restrict__ c2T,
                         unsigned short* __restrict__ WtP) {
    __shared__ unsigned short tile[64][72];
    int blk = blockIdx.x;
    int t = threadIdx.x;

    // ---- repack part (blocks 0..1279) ----
    int idx = blk * 256 + t;
    if (idx < WK * NN) {            // c1T[k][m][p] = cheb1[k][p][m]
        int k = idx / NN, r = idx % NN, m = r / WN, p = r % WN;
        c1T[idx] = f2b(cheb1[(k * WN + p) * WN + m]);
    }
    if (idx < WN * KQ) {            // c2T[n][lq] = cheb2[lq][n]
        int n = idx / KQ, r = idx % KQ;
        c2T[idx] = f2b(cheb2[r * WN + n]);
    }
    if (idx < KC * KC) {            // fragment-packed Wt
        int e = idx & 7, lane = (idx >> 3) & 63, r = idx >> 9;   // r < 50
        int mf = r % 5, kk = (r / 5) % 5, mh = r / 25;
        int lu = mh * 80 + mf * 16 + (lane & 15);    // (l,u) row
        int ki = kk * 32 + (lane >> 4) * 8 + e;      // (k,i) col
        int l = lu >> 5, u = lu & 31, k = ki >> 5, i = ki & 31;
        WtP[idx] = f2b(coefs[((k * WK + l) * WC + i) * WU + u]);
    }

    // ---- prep_x part (all 4096 blocks): xT[b][i][q][p] = x[b][i][p][q] ----
    int bx = blk & 3, by = (blk >> 2) & 3, bi = blk >> 4;
    int p0 = by * 64, q0 = bx * 64;
    const float* src = x + (size_t)bi * NN;
    unsigned short* dst = xT + (size_t)bi * NN;
    int c4 = (t & 15) * 4, r0 = t >> 4;
    for (int it = 0; it < 4; ++it) {
        int r = r0 + it * 16;
        float4 v = *reinterpret_cast<const float4*>(&src[(size_t)(p0 + r) * WN + q0 + c4]);
        tile[r][c4 + 0] = f2b(v.x); tile[r][c4 + 1] = f2b(v.y);
        tile[r][c4 + 2] = f2b(v.z); tile[r][c4 + 3] = f2b(v.w);
    }
    __syncthreads();
    for (int it = 0; it < 4; ++it) {
        int q = r0 + it * 16;
        ushort4 o;
        o.x = tile[c4 + 0][q]; o.y = tile[c4 + 1][q];
        o.z = tile[c4 + 2][q]; o.w = tile[c4 + 3][q];
        *reinterpret_cast<ushort4*>(&dst[(size_t)(q0 + q) * WN + p0 + c4]) = o;
    }
}

// ---------------------------------------------------------------------------
// G1: per (b,i): a[(k*32+i)][m][q] = sum_p c1T[(k,m)][p] * xT[b,i][q][p]
//     r12 PASS version (unchanged): A dbuf, vmcnt(2), XCD-grouped swizzle.
// ---------------------------------------------------------------------------
__global__ __launch_bounds__(512, 4) void g1(const unsigned short* __restrict__ c1T,
                                             const unsigned short* __restrict__ xT,
                                             unsigned short* __restrict__ a, int b_base) {
    __shared__ unsigned short As[2][128 * 64];   // 32 KB
    __shared__ unsigned short Bs[256 * 64];      // 32 KB
    int p = blockIdx.x;
    int gpx = gridDim.x / 80;
    int xcd = p & 7, j = p >> 3;
    int grp = xcd * gpx + j / 10;           // bi group in [0, cur*32)
    int member = j % 10;                    // row-tile 0..9
    int bl = grp >> 5, i = grp & 31;
    int row0 = member * 128;                // (k,m) row base
    int b = b_base + bl;
    const unsigned short* Asrc = c1T;                              // pitch 256
    const unsigned short* Bsrc = xT + (size_t)(b * WC + i) * NN;   // [q][p], pitch 256
    unsigned short* Out = a + (size_t)bl * KC * NN;

    int t = threadIdx.x;
    int w = t >> 6, l = t & 63;
    int wm = (w >> 2) * 64, wn = (w & 3) * 64;
    int lr = l & 15, hi = l >> 4;
    int srow = l >> 3;                       // 0..7 within 8-row chunk
    int scol = ((l & 7) ^ srow) * 8;         // pre-swizzled source col (elems)

    f4 acc[4][4];
    for (int mf = 0; mf < 4; ++mf) for (int nf = 0; nf < 4; ++nf) acc[mf][nf] = (f4)(0.0f);

#define G1_STAGE_A(buf, step) do { \
    int p0_ = (step) * 64; \
    for (int it = 0; it < 2; ++it) { \
        int chunk = it * 8 + w; int row = chunk * 8 + srow; \
        gload16(&Asrc[(size_t)(row0 + row) * 256 + p0_ + scol], &As[buf][chunk * 512]); } \
} while (0)
#define G1_STAGE_B(step) do { \
    int p0_ = (step) * 64; \
    for (int it = 0; it < 4; ++it) { \
        int chunk = it * 8 + w; int row = chunk * 8 + srow; \
        gload16(&Bsrc[(size_t)row * 256 + p0_ + scol], &Bs[chunk * 512]); } \
} while (0)

    G1_STAGE_A(0, 0);                        // prologue: A(0) in flight
    for (int step = 0; step < 4; ++step) {
        int cur = step & 1;
        G1_STAGE_B(step);                    // B(t): 4 loads
        if (step < 3) {
            G1_STAGE_A(cur ^ 1, step + 1);   // A(t+1): 2 loads
            asm volatile("s_waitcnt vmcnt(2)" ::: "memory");
        } else {
            asm volatile("s_waitcnt vmcnt(0)" ::: "memory");
        }
        __builtin_amdgcn_s_barrier();        // tile t visible to all waves
        asm volatile("" ::: "memory");
        for (int kk = 0; kk < 2; ++kk) {
            bf8 af[4], bfr[4];
            for (int mf = 0; mf < 4; ++mf) {
                int r = wm + mf * 16 + lr;
                af[mf] = *(const bf8*)&As[cur][r * 64 + (((kk * 4 + hi) ^ (r & 7)) * 8)];
            }
            for (int nf = 0; nf < 4; ++nf) {
                int rb = wn + nf * 16 + lr;
                bfr[nf] = *(const bf8*)&Bs[rb * 64 + (((kk * 4 + hi) ^ (rb & 7)) * 8)];
            }
            for (int mf = 0; mf < 4; ++mf)
                for (int nf = 0; nf < 4; ++nf)
                    acc[mf][nf] = __builtin_amdgcn_mfma_f32_16x16x32_bf16(af[mf], bfr[nf], acc[mf][nf], 0, 0, 0);
        }
        asm volatile("" ::: "memory");
        __builtin_amdgcn_s_barrier();        // done reading Bs / As[cur]
    }
#undef G1_STAGE_A
#undef G1_STAGE_B
    for (int mf = 0; mf < 4; ++mf)
        for (int nf = 0; nf < 4; ++nf)
            for (int j2 = 0; j2 < 4; ++j2) {
                int grow = row0 + wm + mf * 16 + hi * 4 + j2;   // (k,m)
                int k = grow >> 8, m = grow & 255;
                int q = wn + nf * 16 + lr;
                Out[(size_t)(k * 32 + i) * NN + m * 256 + q] = f2b(acc[mf][nf][j2]);
            }
}

// ---------------------------------------------------------------------------
// G2P: c[(l,u)][(m,q)] = Wt @ a[ki][(m,q)]   (r12 PASS version, unchanged)
// ---------------------------------------------------------------------------
__global__ __launch_bounds__(512, 4) void g2p(const unsigned short* __restrict__ WtP,
                                              const unsigned short* __restrict__ a,
                                              unsigned short* __restrict__ c) {
    __shared__ unsigned short Bt[128 * 172];
    int bl = blockIdx.y;
    int n0 = blockIdx.x * 128;
    const unsigned short* asrc = a + (size_t)bl * KC * NN;
    unsigned short* Out = c + (size_t)bl * KC * NN;
    int t = threadIdx.x;

    for (int s = 0; s < 2; ++s) {
        int task = t + s * 512;
        if (task < 640) {
            int oct = task & 15, kq = task >> 4;
            const unsigned short* src = asrc + (size_t)(kq * 4) * NN + n0 + oct * 8;
            us8 v0 = *(const us8*)&src[0 * NN];
            us8 v1 = *(const us8*)&src[1 * NN];
            us8 v2 = *(const us8*)&src[2 * NN];
            us8 v3 = *(const us8*)&src[3 * NN];
            #pragma unroll
            for (int j = 0; j < 8; ++j) {
                ushort4 wv;
                wv.x = v0[j]; wv.y = v1[j]; wv.z = v2[j]; wv.w = v3[j];
                *reinterpret_cast<ushort4*>(&Bt[(oct * 8 + j) * 172 + kq * 4]) = wv;
            }
        }
    }
    __syncthreads();

    int w = t >> 6, l = t & 63;
    int mh = w >> 2, nq = w & 3;
    int lr = l & 15, hi = l >> 4;
    f4 acc[5][2];
    for (int mf = 0; mf < 5; ++mf) { acc[mf][0] = (f4)(0.0f); acc[mf][1] = (f4)(0.0f); }

    for (int kk = 0; kk < 5; ++kk) {
        int k0 = kk * 32 + hi * 8;
        bf8 bfr[2];
        #pragma unroll
        for (int nf = 0; nf < 2; ++nf) {
            int pix = (nq * 2 + nf) * 16 + lr;
            typedef __attribute__((ext_vector_type(4))) short s4v;
            s4v lo  = *(const s4v*)&Bt[pix * 172 + k0];
            s4v hi4 = *(const s4v*)&Bt[pix * 172 + k0 + 4];
            bfr[nf] = __builtin_shufflevector(lo, hi4, 0, 1, 2, 3, 4, 5, 6, 7);
        }
        #pragma unroll
        for (int mf = 0; mf < 5; ++mf) {
            bf8 afr = *(const bf8*)&WtP[(size_t)((((mh * 5 + kk) * 5 + mf) << 6) + l) * 8];
            acc[mf][0] = __builtin_amdgcn_mfma_f32_16x16x32_bf16(afr, bfr[0], acc[mf][0], 0, 0, 0);
            acc[mf][1] = __builtin_amdgcn_mfma_f32_16x16x32_bf16(afr, bfr[1], acc[mf][1], 0, 0, 0);
        }
    }
    for (int mf = 0; mf < 5; ++mf)
        for (int nf = 0; nf < 2; ++nf)
            for (int j = 0; j < 4; ++j) {
                int row = mh * 80 + mf * 16 + hi * 4 + j;       // (l,u)
                int col = n0 + (nq * 2 + nf) * 16 + lr;         // (m,q)
                Out[(size_t)row * NN + col] = f2b(acc[mf][nf][j]);
            }
}

// ---------------------------------------------------------------------------
// G3: out[b][u][m][n] = sum_{l,q} c[(l*32+u)][(m,q)] * c2T[n][(l,q)]
//     256x256 tile (one u), BK=64, 8 waves (2M x 4N), 2 slots (128 KB).
//     Counted pipeline: tile t's halves issued during iter t-1 in order
//     {A0,B0} early / {A1,B1} mid. Iter t: vmcnt(4) [A0B0 in] -> barrier
//     -> issue A0B0(t+1) -> late waves (needing h1) vmcnt(4) [A1B1 in]
//     -> kk0 MFMA -> issue A1B1(t+1) -> kk1 MFMA -> barrier.
//     Outstanding never < 4; each operand has a full K-step to land.
// ---------------------------------------------------------------------------
__global__ __launch_bounds__(512, 1) void g3(const unsigned short* __restrict__ c,
                                             const unsigned short* __restrict__ c2T,
                                             float* __restrict__ out, int b_base) {
    __shared__ unsigned short As[2][256 * 64];     // 64 KB
    __shared__ unsigned short Bs[2][256 * 64];     // 64 KB
    int bl = blockIdx.y;
    int b = b_base + bl;
    int u = blockIdx.x;                    // 32 u-tiles per batch
    const unsigned short* Csrc = c + (size_t)bl * KC * NN;

    int t_ = threadIdx.x;
    int w = t_ >> 6, l = t_ & 63;
    int wmh = w >> 2;                      // A-half this wave reads
    int wn = (w & 3) * 64;
    int bnh = (w & 3) >> 1;                // B-half this wave reads
    int lr = l & 15, hi = l >> 4;
    int srow = l >> 3;
    int scol = ((l & 7) ^ srow) * 8;
    int late = wmh | bnh;                  // wave needs h1 of A or B

    f4 acc[8][4];
    for (int mf = 0; mf < 8; ++mf) for (int nf = 0; nf < 4; ++nf) acc[mf][nf] = (f4)(0.0f);

    // A half h (m-rows h*128..+128) of K-step kt -> slot s: 2 loads
#define ST_A(s, h, kt) do { \
    int lq_ = (kt) >> 2, q0_ = ((kt) & 3) * 64; \
    const unsigned short* base = Csrc + (size_t)(lq_ * 32 + u) * NN + q0_; \
    for (int it = 0; it < 2; ++it) { \
        int chunk = it * 8 + w; int row = (h) * 128 + chunk * 8 + srow; \
        gload16(&base[(size_t)row * 256 + scol], &As[s][(h) * 8192 + chunk * 512]); } \
} while (0)
    // B half h (n-rows h*128..+128) of K-step kt -> slot s: 2 loads
#define ST_B(s, h, kt) do { \
    const unsigned short* base = c2T + (size_t)((h) * 128) * KQ + (kt) * 64; \
    for (int it = 0; it < 2; ++it) { \
        int chunk = it * 8 + w; int rrow = chunk * 8 + srow; \
        gload16(&base[(size_t)rrow * KQ + scol], &Bs[s][(h) * 8192 + chunk * 512]); } \
} while (0)

    // prologue: tile 0, order A0 B0 (early) then A1 B1 (mid) — 8 loads
    ST_A(0, 0, 0); ST_B(0, 0, 0); ST_A(0, 1, 0); ST_B(0, 1, 0);

    for (int t = 0; t < 20; ++t) {
        int s = t & 1;
        // entry: outstanding <= 8 = {A0,B0(t)}[4] older + {A1,B1(t)}[4]
        asm volatile("s_waitcnt vmcnt(4)" ::: "memory");   // A0,B0(t) landed
        __builtin_amdgcn_s_barrier();        // + all reads of slot s^1 done
        asm volatile("" ::: "memory");
        if (t < 19) { ST_A(s ^ 1, 0, t + 1); ST_B(s ^ 1, 0, t + 1); }  // 4 issues
        if (late) {
            // outstanding: {A1,B1(t)}[4] + {A0,B0(t+1)}[4 if t<19]
            if (t < 19) asm volatile("s_waitcnt vmcnt(4)" ::: "memory");
            else        asm volatile("s_waitcnt vmcnt(0)" ::: "memory");
        }
        const unsigned short* A = As[s];
        const unsigned short* B = Bs[s];
        // ---- kk = 0 ----
        {
            bf8 af[8], bfr[4];
            #pragma unroll
            for (int mf = 0; mf < 8; ++mf) {
                int r = wmh * 128 + mf * 16 + lr;
                af[mf] = *(const bf8*)&A[r * 64 + ((hi ^ (r & 7)) * 8)];
            }
            #pragma unroll
            for (int nf = 0; nf < 4; ++nf) {
                int rb = wn + nf * 16 + lr;
                bfr[nf] = *(const bf8*)&B[rb * 64 + ((hi ^ (rb & 7)) * 8)];
            }
            __builtin_amdgcn_s_setprio(1);
            #pragma unroll
            for (int mf = 0; mf < 8; ++mf)
                #pragma unroll
                for (int nf = 0; nf < 4; ++nf)
                    acc[mf][nf] = __builtin_amdgcn_mfma_f32_16x16x32_bf16(af[mf], bfr[nf], acc[mf][nf], 0, 0, 0);
            __builtin_amdgcn_s_setprio(0);
        }
        if (t < 19) { ST_A(s ^ 1, 1, t + 1); ST_B(s ^ 1, 1, t + 1); }  // mid issues
        // ---- kk = 1 ----
        {
            bf8 af[8], bfr[4];
            #pragma unroll
            for (int mf = 0; mf < 8; ++mf) {
                int r = wmh * 128 + mf * 16 + lr;
                af[mf] = *(const bf8*)&A[r * 64 + (((4 + hi) ^ (r & 7)) * 8)];
            }
            #pragma unroll
            for (int nf = 0; nf < 4; ++nf) {
                int rb = wn + nf * 16 + lr;
                bfr[nf] = *(const bf8*)&B[rb * 64 + (((4 + hi) ^ (rb & 7)) * 8)];
            }
            __builtin_amdgcn_s_setprio(1);
            #pragma unroll
            for (int mf = 0; mf < 8; ++mf)
                #pragma unroll
                for (int nf = 0; nf < 4; ++nf)
                    acc[mf][nf] = __builtin_amdgcn_mfma_f32_16x16x32_bf16(af[mf], bfr[nf], acc[mf][nf], 0, 0, 0);
            __builtin_amdgcn_s_setprio(0);
        }
        asm volatile("" ::: "memory");
        __builtin_amdgcn_s_barrier();        // reads of slot s done
    }
#undef ST_A
#undef ST_B
    for (int mf = 0; mf < 8; ++mf)
        for (int nf = 0; nf < 4; ++nf)
            for (int j = 0; j < 4; ++j) {
                int m = wmh * 128 + mf * 16 + hi * 4 + j;
                int n = wn + nf * 16 + lr;
                out[((size_t)(b * WU + u) * WN + m) * WN + n] = acc[mf][nf][j];
            }
}

// ---------------------------------------------------------------------------
extern "C" void kernel_launch(void* const* d_in, const int* in_sizes, int n_in,
                              void* d_out, int out_size, void* d_ws, size_t ws_size,
                              hipStream_t stream) {
    const float* x     = (const float*)d_in[0];
    const float* cheb1 = (const float*)d_in[1];
    const float* cheb2 = (const float*)d_in[2];
    const float* coefs = (const float*)d_in[3];
    float* out = (float*)d_out;
    unsigned short* ws = (unsigned short*)d_ws;

    size_t off = 0;
    unsigned short* xT  = ws + off; off += (size_t)WB * WC * NN;
    unsigned short* c1T = ws + off; off += (size_t)WK * NN;
    unsigned short* c2T = ws + off; off += (size_t)WN * KQ;
    unsigned short* WtP = ws + off; off += (size_t)KC * KC;
    size_t fixed_elems = off;
    size_t a1 = (size_t)KC * NN;                 // one batch of a or c (elems)

    prep_all<<<4096, 256, 0, stream>>>(x, cheb1, cheb2, coefs, xT, c1T, c2T, WtP);

    size_t avail = ws_size / 2;
    size_t rem = avail > fixed_elems ? avail - fixed_elems : 0;

    if (rem >= 9 * a1) {
        // full-c path: chunk a by nb batches, single g3 over all 8
        int nb = (int)((rem - 8 * a1) / a1);
        if (nb < 1) nb = 1;
        if (nb > WB) nb = WB;
        unsigned short* a_ = ws + fixed_elems;
        unsigned short* c_ = a_ + (size_t)nb * a1;
        for (int b0 = 0; b0 < WB; b0 += nb) {
            int cur = (WB - b0 < nb) ? (WB - b0) : nb;
            g1<<<dim3(cur * 320), 512, 0, stream>>>(c1T, xT, a_, b0);
            g2p<<<dim3(512, cur), 512, 0, stream>>>(WtP, a_, c_ + (size_t)b0 * a1);
        }
        g3<<<dim3(32, WB), 512, 0, stream>>>(c_, c2T, out, 0);
    } else {
        // chunked fallback
        size_t per_b = 2 * a1;
        int nb = (int)(rem / per_b);
        if (nb < 1) nb = 1;
        if (nb > WB) nb = WB;
        unsigned short* a_ = ws + fixed_elems;
        unsigned short* c_ = a_ + (size_t)nb * a1;
        for (int b0 = 0; b0 < WB; b0 += nb) {
            int cur = (WB - b0 < nb) ? (WB - b0) : nb;
            g1<<<dim3(cur * 320), 512, 0, stream>>>(c1T, xT, a_, b0);
            g2p<<<dim3(512, cur), 512, 0, stream>>>(WtP, a_, c_);
            g3<<<dim3(32, cur), 512, 0, stream>>>(c_, c2T, out, b0);
        }
    }
}

// Round 15
// 256.114 us; speedup vs baseline: 1.0540x; 1.0473x over previous
//
#include <hip/hip_runtime.h>
#include <stdint.h>

#define WB 8
#define WC 32
#define WU 32
#define WK 5
#define WN 256
#define NN 65536     // 256*256
#define KC 160       // WK*WC
#define KQ 1280      // WK*WN

typedef __attribute__((ext_vector_type(8))) short bf8;     // 8 x bf16
typedef __attribute__((ext_vector_type(8))) unsigned short us8;
typedef __attribute__((ext_vector_type(4))) float f4;

__device__ __forceinline__ unsigned short f2b(float f) {
    union { float f; uint32_t u; } v; v.f = f;
    uint32_t u = v.u;
    return (unsigned short)((u + 0x7FFFu + ((u >> 16) & 1u)) >> 16);  // RNE
}

// async global->LDS, 16B per lane; lds base must be wave-uniform (m97 pattern)
__device__ __forceinline__ void gload16(const unsigned short* g, unsigned short* l) {
    __builtin_amdgcn_global_load_lds(
        (const __attribute__((address_space(1))) unsigned int*)g,
        (__attribute__((address_space(3))) unsigned int*)l, 16, 0, 0);
}

// ---------------------------------------------------------------------------
// P0+P1 merged: xT transpose + c1T/c2T/WtP repacks in ONE dispatch (r14).
// ---------------------------------------------------------------------------
__global__ void prep_all(const float* __restrict__ x,
                         const float* __restrict__ cheb1,
                         const float* __restrict__ cheb2,
                         const float* __restrict__ coefs,
                         unsigned short* __restrict__ xT,
                         unsigned short* __restrict__ c1T,
                         unsigned short* __restrict__ c2T,
                         unsigned short* __restrict__ WtP) {
    __shared__ unsigned short tile[64][72];
    int blk = blockIdx.x;
    int t = threadIdx.x;

    // ---- repack part (blocks 0..1279) ----
    int idx = blk * 256 + t;
    if (idx < WK * NN) {            // c1T[k][m][p] = cheb1[k][p][m]
        int k = idx / NN, r = idx % NN, m = r / WN, p = r % WN;
        c1T[idx] = f2b(cheb1[(k * WN + p) * WN + m]);
    }
    if (idx < WN * KQ) {            // c2T[n][lq] = cheb2[lq][n]
        int n = idx / KQ, r = idx % KQ;
        c2T[idx] = f2b(cheb2[r * WN + n]);
    }
    if (idx < KC * KC) {            // fragment-packed Wt
        int e = idx & 7, lane = (idx >> 3) & 63, r = idx >> 9;   // r < 50
        int mf = r % 5, kk = (r / 5) % 5, mh = r / 25;
        int lu = mh * 80 + mf * 16 + (lane & 15);    // (l,u) row
        int ki = kk * 32 + (lane >> 4) * 8 + e;      // (k,i) col
        int l = lu >> 5, u = lu & 31, k = ki >> 5, i = ki & 31;
        WtP[idx] = f2b(coefs[((k * WK + l) * WC + i) * WU + u]);
    }

    // ---- prep_x part (all 4096 blocks): xT[b][i][q][p] = x[b][i][p][q] ----
    int bx = blk & 3, by = (blk >> 2) & 3, bi = blk >> 4;
    int p0 = by * 64, q0 = bx * 64;
    const float* src = x + (size_t)bi * NN;
    unsigned short* dst = xT + (size_t)bi * NN;
    int c4 = (t & 15) * 4, r0 = t >> 4;
    for (int it = 0; it < 4; ++it) {
        int r = r0 + it * 16;
        float4 v = *reinterpret_cast<const float4*>(&src[(size_t)(p0 + r) * WN + q0 + c4]);
        tile[r][c4 + 0] = f2b(v.x); tile[r][c4 + 1] = f2b(v.y);
        tile[r][c4 + 2] = f2b(v.z); tile[r][c4 + 3] = f2b(v.w);
    }
    __syncthreads();
    for (int it = 0; it < 4; ++it) {
        int q = r0 + it * 16;
        ushort4 o;
        o.x = tile[c4 + 0][q]; o.y = tile[c4 + 1][q];
        o.z = tile[c4 + 2][q]; o.w = tile[c4 + 3][q];
        *reinterpret_cast<ushort4*>(&dst[(size_t)(q0 + q) * WN + p0 + c4]) = o;
    }
}

// ---------------------------------------------------------------------------
// G1: per (b,i): a[(k*32+i)][m][q] = sum_p c1T[(k,m)][p] * xT[b,i][q][p]
//     r12 PASS version: A dbuf, vmcnt(2), XCD-grouped swizzle.
// ---------------------------------------------------------------------------
__global__ __launch_bounds__(512, 4) void g1(const unsigned short* __restrict__ c1T,
                                             const unsigned short* __restrict__ xT,
                                             unsigned short* __restrict__ a, int b_base) {
    __shared__ unsigned short As[2][128 * 64];   // 32 KB
    __shared__ unsigned short Bs[256 * 64];      // 32 KB
    int p = blockIdx.x;
    int gpx = gridDim.x / 80;
    int xcd = p & 7, j = p >> 3;
    int grp = xcd * gpx + j / 10;           // bi group in [0, cur*32)
    int member = j % 10;                    // row-tile 0..9
    int bl = grp >> 5, i = grp & 31;
    int row0 = member * 128;                // (k,m) row base
    int b = b_base + bl;
    const unsigned short* Asrc = c1T;                              // pitch 256
    const unsigned short* Bsrc = xT + (size_t)(b * WC + i) * NN;   // [q][p], pitch 256
    unsigned short* Out = a + (size_t)bl * KC * NN;

    int t = threadIdx.x;
    int w = t >> 6, l = t & 63;
    int wm = (w >> 2) * 64, wn = (w & 3) * 64;
    int lr = l & 15, hi = l >> 4;
    int srow = l >> 3;                       // 0..7 within 8-row chunk
    int scol = ((l & 7) ^ srow) * 8;         // pre-swizzled source col (elems)

    f4 acc[4][4];
    for (int mf = 0; mf < 4; ++mf) for (int nf = 0; nf < 4; ++nf) acc[mf][nf] = (f4)(0.0f);

#define G1_STAGE_A(buf, step) do { \
    int p0_ = (step) * 64; \
    for (int it = 0; it < 2; ++it) { \
        int chunk = it * 8 + w; int row = chunk * 8 + srow; \
        gload16(&Asrc[(size_t)(row0 + row) * 256 + p0_ + scol], &As[buf][chunk * 512]); } \
} while (0)
#define G1_STAGE_B(step) do { \
    int p0_ = (step) * 64; \
    for (int it = 0; it < 4; ++it) { \
        int chunk = it * 8 + w; int row = chunk * 8 + srow; \
        gload16(&Bsrc[(size_t)row * 256 + p0_ + scol], &Bs[chunk * 512]); } \
} while (0)

    G1_STAGE_A(0, 0);                        // prologue: A(0) in flight
    for (int step = 0; step < 4; ++step) {
        int cur = step & 1;
        G1_STAGE_B(step);                    // B(t): 4 loads
        if (step < 3) {
            G1_STAGE_A(cur ^ 1, step + 1);   // A(t+1): 2 loads
            asm volatile("s_waitcnt vmcnt(2)" ::: "memory");
        } else {
            asm volatile("s_waitcnt vmcnt(0)" ::: "memory");
        }
        __builtin_amdgcn_s_barrier();        // tile t visible to all waves
        asm volatile("" ::: "memory");
        for (int kk = 0; kk < 2; ++kk) {
            bf8 af[4], bfr[4];
            for (int mf = 0; mf < 4; ++mf) {
                int r = wm + mf * 16 + lr;
                af[mf] = *(const bf8*)&As[cur][r * 64 + (((kk * 4 + hi) ^ (r & 7)) * 8)];
            }
            for (int nf = 0; nf < 4; ++nf) {
                int rb = wn + nf * 16 + lr;
                bfr[nf] = *(const bf8*)&Bs[rb * 64 + (((kk * 4 + hi) ^ (rb & 7)) * 8)];
            }
            for (int mf = 0; mf < 4; ++mf)
                for (int nf = 0; nf < 4; ++nf)
                    acc[mf][nf] = __builtin_amdgcn_mfma_f32_16x16x32_bf16(af[mf], bfr[nf], acc[mf][nf], 0, 0, 0);
        }
        asm volatile("" ::: "memory");
        __builtin_amdgcn_s_barrier();        // done reading Bs / As[cur]
    }
#undef G1_STAGE_A
#undef G1_STAGE_B
    for (int mf = 0; mf < 4; ++mf)
        for (int nf = 0; nf < 4; ++nf)
            for (int j2 = 0; j2 < 4; ++j2) {
                int grow = row0 + wm + mf * 16 + hi * 4 + j2;   // (k,m)
                int k = grow >> 8, m = grow & 255;
                int q = wn + nf * 16 + lr;
                Out[(size_t)(k * 32 + i) * NN + m * 256 + q] = f2b(acc[mf][nf][j2]);
            }
}

// ---------------------------------------------------------------------------
// G2P: c[(l,u)][(m,q)] = Wt @ a[ki][(m,q)]   (r12 PASS version)
// ---------------------------------------------------------------------------
__global__ __launch_bounds__(512, 4) void g2p(const unsigned short* __restrict__ WtP,
                                              const unsigned short* __restrict__ a,
                                              unsigned short* __restrict__ c) {
    __shared__ unsigned short Bt[128 * 172];
    int bl = blockIdx.y;
    int n0 = blockIdx.x * 128;
    const unsigned short* asrc = a + (size_t)bl * KC * NN;
    unsigned short* Out = c + (size_t)bl * KC * NN;
    int t = threadIdx.x;

    for (int s = 0; s < 2; ++s) {
        int task = t + s * 512;
        if (task < 640) {
            int oct = task & 15, kq = task >> 4;
            const unsigned short* src = asrc + (size_t)(kq * 4) * NN + n0 + oct * 8;
            us8 v0 = *(const us8*)&src[0 * NN];
            us8 v1 = *(const us8*)&src[1 * NN];
            us8 v2 = *(const us8*)&src[2 * NN];
            us8 v3 = *(const us8*)&src[3 * NN];
            #pragma unroll
            for (int j = 0; j < 8; ++j) {
                ushort4 wv;
                wv.x = v0[j]; wv.y = v1[j]; wv.z = v2[j]; wv.w = v3[j];
                *reinterpret_cast<ushort4*>(&Bt[(oct * 8 + j) * 172 + kq * 4]) = wv;
            }
        }
    }
    __syncthreads();

    int w = t >> 6, l = t & 63;
    int mh = w >> 2, nq = w & 3;
    int lr = l & 15, hi = l >> 4;
    f4 acc[5][2];
    for (int mf = 0; mf < 5; ++mf) { acc[mf][0] = (f4)(0.0f); acc[mf][1] = (f4)(0.0f); }

    for (int kk = 0; kk < 5; ++kk) {
        int k0 = kk * 32 + hi * 8;
        bf8 bfr[2];
        #pragma unroll
        for (int nf = 0; nf < 2; ++nf) {
            int pix = (nq * 2 + nf) * 16 + lr;
            typedef __attribute__((ext_vector_type(4))) short s4v;
            s4v lo  = *(const s4v*)&Bt[pix * 172 + k0];
            s4v hi4 = *(const s4v*)&Bt[pix * 172 + k0 + 4];
            bfr[nf] = __builtin_shufflevector(lo, hi4, 0, 1, 2, 3, 4, 5, 6, 7);
        }
        #pragma unroll
        for (int mf = 0; mf < 5; ++mf) {
            bf8 afr = *(const bf8*)&WtP[(size_t)((((mh * 5 + kk) * 5 + mf) << 6) + l) * 8];
            acc[mf][0] = __builtin_amdgcn_mfma_f32_16x16x32_bf16(afr, bfr[0], acc[mf][0], 0, 0, 0);
            acc[mf][1] = __builtin_amdgcn_mfma_f32_16x16x32_bf16(afr, bfr[1], acc[mf][1], 0, 0, 0);
        }
    }
    for (int mf = 0; mf < 5; ++mf)
        for (int nf = 0; nf < 2; ++nf)
            for (int j = 0; j < 4; ++j) {
                int row = mh * 80 + mf * 16 + hi * 4 + j;       // (l,u)
                int col = n0 + (nq * 2 + nf) * 16 + lr;         // (m,q)
                Out[(size_t)row * NN + col] = f2b(acc[mf][nf][j]);
            }
}

// ---------------------------------------------------------------------------
// G3: out[b][u][m][n] = sum_{l,q} c[(l*32+u)][(m,q)] * c2T[n][(l,q)]
//     r9 PASS version (permanent): 128x256 tile, A dbuf 2x16KB + B 32KB
//     (64KB -> 2 blocks/CU), stage-ahead-1 on A, vmcnt(2), 2 barriers/step.
// ---------------------------------------------------------------------------
__global__ __launch_bounds__(512, 4) void g3(const unsigned short* __restrict__ c,
                                             const unsigned short* __restrict__ c2T,
                                             float* __restrict__ out, int b_base) {
    __shared__ unsigned short As[2][128 * 64];     // 32 KB
    __shared__ unsigned short Bs[256 * 64];        // 32 KB
    int bl = blockIdx.y;
    int b = b_base + bl;
    int R0 = blockIdx.x * 128;             // (u,m); u fixed per block
    int u = R0 >> 8, m0 = R0 & 255;
    const unsigned short* Csrc = c + (size_t)bl * KC * NN;

    int t = threadIdx.x;
    int w = t >> 6, l = t & 63;
    int wm = (w >> 2) * 64, wn = (w & 3) * 64;
    int lr = l & 15, hi = l >> 4;
    int srow = l >> 3;
    int scol = ((l & 7) ^ srow) * 8;

    f4 acc[4][4];
    for (int mf = 0; mf < 4; ++mf) for (int nf = 0; nf < 4; ++nf) acc[mf][nf] = (f4)(0.0f);

#define G3_STAGE_A(buf, step) do { \
    int lq_ = (step) >> 2, q0_ = ((step) & 3) * 64; \
    const unsigned short* Arow0 = Csrc + (size_t)(lq_ * 32 + u) * NN + (size_t)m0 * 256 + q0_; \
    for (int it = 0; it < 2; ++it) { \
        int chunk = it * 8 + w; int row = chunk * 8 + srow; \
        gload16(&Arow0[(size_t)row * 256 + scol], &As[buf][chunk * 512]); } \
} while (0)
#define G3_STAGE_B(step) do { \
    const unsigned short* Brow0 = c2T + (step) * 64; \
    for (int it = 0; it < 4; ++it) { \
        int chunk = it * 8 + w; int row = chunk * 8 + srow; \
        gload16(&Brow0[(size_t)row * KQ + scol], &Bs[chunk * 512]); } \
} while (0)

    G3_STAGE_A(0, 0);                        // prologue: A(0) in flight
    for (int step = 0; step < 20; ++step) {
        int cur = step & 1;
        G3_STAGE_B(step);                    // B(t): 4 loads, L2-hot
        if (step < 19) {
            G3_STAGE_A(cur ^ 1, step + 1);   // A(t+1): 2 loads, one step early
            asm volatile("s_waitcnt vmcnt(2)" ::: "memory");
        } else {
            asm volatile("s_waitcnt vmcnt(0)" ::: "memory");
        }
        __builtin_amdgcn_s_barrier();        // tile t visible to all waves
        asm volatile("" ::: "memory");
        for (int kk = 0; kk < 2; ++kk) {
            bf8 af[4], bfr[4];
            for (int mf = 0; mf < 4; ++mf) {
                int r = wm + mf * 16 + lr;
                af[mf] = *(const bf8*)&As[cur][r * 64 + (((kk * 4 + hi) ^ (r & 7)) * 8)];
            }
            for (int nf = 0; nf < 4; ++nf) {
                int rb = wn + nf * 16 + lr;
                bfr[nf] = *(const bf8*)&Bs[rb * 64 + (((kk * 4 + hi) ^ (rb & 7)) * 8)];
            }
            for (int mf = 0; mf < 4; ++mf)
                for (int nf = 0; nf < 4; ++nf)
                    acc[mf][nf] = __builtin_amdgcn_mfma_f32_16x16x32_bf16(af[mf], bfr[nf], acc[mf][nf], 0, 0, 0);
        }
        asm volatile("" ::: "memory");
        __builtin_amdgcn_s_barrier();        // done reading Bs / As[cur]
    }
#undef G3_STAGE_A
#undef G3_STAGE_B
    for (int mf = 0; mf < 4; ++mf)
        for (int nf = 0; nf < 4; ++nf)
            for (int j = 0; j < 4; ++j) {
                int m = m0 + wm + mf * 16 + hi * 4 + j;
                int n = wn + nf * 16 + lr;
                out[((size_t)(b * WU + u) * WN + m) * WN + n] = acc[mf][nf][j];
            }
}

// ---------------------------------------------------------------------------
extern "C" void kernel_launch(void* const* d_in, const int* in_sizes, int n_in,
                              void* d_out, int out_size, void* d_ws, size_t ws_size,
                              hipStream_t stream) {
    const float* x     = (const float*)d_in[0];
    const float* cheb1 = (const float*)d_in[1];
    const float* cheb2 = (const float*)d_in[2];
    const float* coefs = (const float*)d_in[3];
    float* out = (float*)d_out;
    unsigned short* ws = (unsigned short*)d_ws;

    size_t off = 0;
    unsigned short* xT  = ws + off; off += (size_t)WB * WC * NN;
    unsigned short* c1T = ws + off; off += (size_t)WK * NN;
    unsigned short* c2T = ws + off; off += (size_t)WN * KQ;
    unsigned short* WtP = ws + off; off += (size_t)KC * KC;
    size_t fixed_elems = off;
    size_t a1 = (size_t)KC * NN;                 // one batch of a or c (elems)

    prep_all<<<4096, 256, 0, stream>>>(x, cheb1, cheb2, coefs, xT, c1T, c2T, WtP);

    size_t avail = ws_size / 2;
    size_t rem = avail > fixed_elems ? avail - fixed_elems : 0;

    if (rem >= 9 * a1) {
        // full-c path: chunk a by nb batches, single g3 over all 8
        int nb = (int)((rem - 8 * a1) / a1);
        if (nb < 1) nb = 1;
        if (nb > WB) nb = WB;
        unsigned short* a_ = ws + fixed_elems;
        unsigned short* c_ = a_ + (size_t)nb * a1;
        for (int b0 = 0; b0 < WB; b0 += nb) {
            int cur = (WB - b0 < nb) ? (WB - b0) : nb;
            g1<<<dim3(cur * 320), 512, 0, stream>>>(c1T, xT, a_, b0);
            g2p<<<dim3(512, cur), 512, 0, stream>>>(WtP, a_, c_ + (size_t)b0 * a1);
        }
        g3<<<dim3(64, WB), 512, 0, stream>>>(c_, c2T, out, 0);
    } else {
        // chunked fallback
        size_t per_b = 2 * a1;
        int nb = (int)(rem / per_b);
        if (nb < 1) nb = 1;
        if (nb > WB) nb = WB;
        unsigned short* a_ = ws + fixed_elems;
        unsigned short* c_ = a_ + (size_t)nb * a1;
        for (int b0 = 0; b0 < WB; b0 += nb) {
            int cur = (WB - b0 < nb) ? (WB - b0) : nb;
            g1<<<dim3(cur * 320), 512, 0, stream>>>(c1T, xT, a_, b0);
            g2p<<<dim3(512, cur), 512, 0, stream>>>(WtP, a_, c_);
            g3<<<dim3(64, cur), 512, 0, stream>>>(c_, c2T, out, b0);
        }
    }
}